// Round 1
// baseline (614.851 us; speedup 1.0000x reference)
//
#include <hip/hip_runtime.h>

#define TPB 256

// ---------------------------------------------------------------------------
// pass1: h = feats@W1+b1 stats (sum, sumsq per channel), mask branch output,
//        pooled per-batch sums. Each thread owns channel ch = tid&31 and keeps
//        W1[:,ch], maskW1[:,ch] in registers (64 VGPRs) so the inner loop is
//        1 LDS broadcast read + 2 FMA per k-element.
// ---------------------------------------------------------------------------
__global__ __launch_bounds__(TPB) void pass1_kernel(
    const float* __restrict__ feats, const int* __restrict__ bidx,
    const float* __restrict__ w1, const float* __restrict__ b1,
    const float* __restrict__ mw1, const float* __restrict__ mb1,
    const float* __restrict__ mw2, const float* __restrict__ mb2,
    float* __restrict__ mask_out,
    float* __restrict__ ws_sum, float* __restrict__ ws_sq,
    float* __restrict__ ws_pool, int N)
{
    __shared__ float fld[32][32];      // staged feature rows (broadcast reads)
    __shared__ float mlds[32][33];     // relu(m)*mw2[ch], +1 pad kills bank conflict
    __shared__ float red[8][32];       // stat reduction
    __shared__ float pool[8][32];      // per-block pooled accumulation (B=8)
    __shared__ int   blds[32];

    const int tid = threadIdx.x;
    const int ch  = tid & 31;
    const int rg  = tid >> 5;

    float w1c[32], mw1c[32];
#pragma unroll
    for (int i = 0; i < 32; ++i) {
        w1c[i]  = w1[i * 32 + ch];
        mw1c[i] = mw1[i * 32 + ch];
    }
    const float b1c  = b1[ch];
    const float mb1c = mb1[ch];
    const float mw2c = mw2[ch];
    const float mb2s = mb2[0];

    pool[rg][ch] = 0.f;

    float lsum = 0.f, lsq = 0.f;
    float pacc = 0.f;
    int   curb = -1;

    const int groups = (N + 31) >> 5;
    const int gpb = (groups + gridDim.x - 1) / gridDim.x;  // contiguous chunks
    const int g0 = blockIdx.x * gpb;
    const int g1 = min(g0 + gpb, groups);

    for (int g = g0; g < g1; ++g) {
        const int row0 = g << 5;
        {   // stage 32 rows x 32 ch, one float4 per thread, fully coalesced
            const int r  = tid >> 3;
            const int c4 = (tid & 7) << 2;
            const int row = row0 + r;
            float4 v = make_float4(0.f, 0.f, 0.f, 0.f);
            if (row < N) v = *(const float4*)(feats + (size_t)row * 32 + c4);
            *(float4*)(&fld[r][c4]) = v;
            if (tid < 32) blds[tid] = (row0 + tid < N) ? bidx[row0 + tid] : -1;
        }
        __syncthreads();
#pragma unroll
        for (int k = 0; k < 4; ++k) {
            const int r   = rg * 4 + k;
            const int row = row0 + r;
            if (row < N) {
                float h = b1c, m = mb1c;
#pragma unroll
                for (int i = 0; i < 32; ++i) {
                    const float f = fld[r][i];
                    h = fmaf(f, w1c[i], h);
                    m = fmaf(f, mw1c[i], m);
                }
                lsum += h;
                lsq = fmaf(h, h, lsq);
                mlds[r][ch] = fmaxf(m, 0.f) * mw2c;
                // pooled: batch_idxs sorted + contiguous chunks => flush is rare
                const int b = blds[r];
                if (b != curb) {
                    if (curb >= 0) atomicAdd(&pool[curb][ch], pacc);
                    curb = b;
                    pacc = 0.f;
                }
                pacc += fld[r][ch];
            }
        }
        __syncthreads();
        if (tid < 32) {   // mask score: 32-wide dot from padded LDS, coalesced write
            const int row = row0 + tid;
            if (row < N) {
                float acc = mb2s;
#pragma unroll
                for (int i = 0; i < 32; ++i) acc += mlds[tid][i];
                mask_out[row] = acc;
            }
        }
        __syncthreads();
    }

    if (curb >= 0) atomicAdd(&pool[curb][ch], pacc);
    red[rg][ch] = lsum;
    __syncthreads();
    if (tid < 32) {
        float s = 0.f;
#pragma unroll
        for (int r = 0; r < 8; ++r) s += red[r][tid];
        atomicAdd(&ws_sum[tid], s);
    }
    {   // pool entry tid = (rg, ch); all flushes visible after the sync above
        const float pv = pool[rg][ch];
        if (pv != 0.f) atomicAdd(&ws_pool[rg * 32 + ch], pv);
    }
    __syncthreads();
    red[rg][ch] = lsq;
    __syncthreads();
    if (tid < 32) {
        float s = 0.f;
#pragma unroll
        for (int r = 0; r < 8; ++r) s += red[r][tid];
        atomicAdd(&ws_sq[tid], s);
    }
}

// ---------------------------------------------------------------------------
// finalize: single block. BN stats -> folded W1', b1' in ws; segment counts
// via binary search on the sorted batch_idxs (no extra O(N) pass); pooled +
// iou_scores outputs.
// ---------------------------------------------------------------------------
__global__ __launch_bounds__(TPB) void finalize_kernel(
    const int* __restrict__ bidx,
    const float* __restrict__ gamma, const float* __restrict__ beta,
    const float* __restrict__ w1, const float* __restrict__ b1,
    const float* __restrict__ iw, const float* __restrict__ ib,
    const float* __restrict__ ws_sum, const float* __restrict__ ws_sq,
    const float* __restrict__ ws_pool,
    float* __restrict__ ws_w1f, float* __restrict__ ws_b1f,
    float* __restrict__ pooled_out, float* __restrict__ iou_out,
    int N, int B)
{
    __shared__ float s_s[32];
    __shared__ float s_pooled[256];
    __shared__ int   s_lb[33];

    const int tid = threadIdx.x;
    if (tid <= B) {   // lower_bound(bidx, tid): first idx with bidx[idx] >= tid
        int lo = 0, hi = N;
        while (lo < hi) {
            const int mid = (lo + hi) >> 1;
            if (bidx[mid] < tid) lo = mid + 1; else hi = mid;
        }
        s_lb[tid] = lo;
    }
    if (tid < 32) {
        const float invN = 1.f / (float)N;
        const float mu  = ws_sum[tid] * invN;
        const float var = ws_sq[tid] * invN - mu * mu;
        const float s   = gamma[tid] * rsqrtf(var + 1e-4f);
        s_s[tid] = s;
        ws_b1f[tid] = (b1[tid] - mu) * s + beta[tid];
    }
    __syncthreads();
    for (int idx = tid; idx < 1024; idx += TPB)
        ws_w1f[idx] = w1[idx] * s_s[idx & 31];
    if (tid < B * 32) {
        const int b = tid >> 5;
        const float cnt = fmaxf((float)(s_lb[b + 1] - s_lb[b]), 1.f);
        const float p = ws_pool[tid] / cnt;
        s_pooled[tid]   = p;
        pooled_out[tid] = p;
    }
    __syncthreads();
    if (tid < B) {
        float acc = ib[0];
#pragma unroll
        for (int i = 0; i < 32; ++i) acc = fmaf(s_pooled[tid * 32 + i], iw[i], acc);
        iou_out[tid] = acc;
    }
}

// ---------------------------------------------------------------------------
// pass2: h' = feats@W1'+b1' (BN folded), relu, @W2 -> pt_offsets.
// relu(h) goes through padded LDS; 96 threads do the 32x3 projection with a
// fully coalesced 96-float store per 32-row tile.
// ---------------------------------------------------------------------------
__global__ __launch_bounds__(TPB) void pass2_kernel(
    const float* __restrict__ feats,
    const float* __restrict__ ws_w1f, const float* __restrict__ ws_b1f,
    const float* __restrict__ w2, const float* __restrict__ b2,
    float* __restrict__ pt_out, int N)
{
    __shared__ float fld[32][32];
    __shared__ float plds[32][33];
    __shared__ float w2s[96];
    __shared__ float b2s[3];

    const int tid = threadIdx.x;
    const int ch  = tid & 31;
    const int rg  = tid >> 5;

    float wc[32];
#pragma unroll
    for (int i = 0; i < 32; ++i) wc[i] = ws_w1f[i * 32 + ch];
    const float b1f = ws_b1f[ch];

    if (tid < 96) w2s[tid] = w2[tid];
    if (tid < 3)  b2s[tid] = b2[tid];

    const int rr = tid / 3;        // reducer row (valid for tid < 96)
    const int rk = tid - rr * 3;   // output component 0..2

    const int groups = (N + 31) >> 5;
    const int gpb = (groups + gridDim.x - 1) / gridDim.x;
    const int g0 = blockIdx.x * gpb;
    const int g1 = min(g0 + gpb, groups);

    __syncthreads();

    for (int g = g0; g < g1; ++g) {
        const int row0 = g << 5;
        {
            const int r  = tid >> 3;
            const int c4 = (tid & 7) << 2;
            const int row = row0 + r;
            float4 v = make_float4(0.f, 0.f, 0.f, 0.f);
            if (row < N) v = *(const float4*)(feats + (size_t)row * 32 + c4);
            *(float4*)(&fld[r][c4]) = v;
        }
        __syncthreads();
#pragma unroll
        for (int k = 0; k < 4; ++k) {
            const int r   = rg * 4 + k;
            const int row = row0 + r;
            if (row < N) {
                float h = b1f;
#pragma unroll
                for (int i = 0; i < 32; ++i) h = fmaf(fld[r][i], wc[i], h);
                plds[r][ch] = fmaxf(h, 0.f);
            }
        }
        __syncthreads();
        if (tid < 96) {
            const int row = row0 + rr;
            if (row < N) {
                float acc = b2s[rk];
#pragma unroll
                for (int i = 0; i < 32; ++i)
                    acc = fmaf(plds[rr][i], w2s[i * 3 + rk], acc);
                pt_out[(size_t)row0 * 3 + tid] = acc;   // coalesced: row0*3+tid
            }
        }
        __syncthreads();
    }
}

extern "C" void kernel_launch(void* const* d_in, const int* in_sizes, int n_in,
                              void* d_out, int out_size, void* d_ws, size_t ws_size,
                              hipStream_t stream) {
    const float* feats = (const float*)d_in[0];
    const int*   bidx  = (const int*)d_in[1];
    const float* w1    = (const float*)d_in[2];
    const float* b1    = (const float*)d_in[3];
    const float* gamma = (const float*)d_in[4];
    const float* beta  = (const float*)d_in[5];
    const float* w2    = (const float*)d_in[6];
    const float* b2    = (const float*)d_in[7];
    const float* mw1   = (const float*)d_in[8];
    const float* mb1   = (const float*)d_in[9];
    const float* mw2   = (const float*)d_in[10];
    const float* mb2   = (const float*)d_in[11];
    const float* iw    = (const float*)d_in[12];
    const float* ib    = (const float*)d_in[13];

    const int N = in_sizes[0] / 32;
    const int B = (out_size - 4 * N) / 33;   // out = 3N + N + 32B + B

    float* out    = (float*)d_out;
    float* pt     = out;                       // [N,3]
    float* mask   = out + (size_t)3 * N;       // [N,1]
    float* pooled = out + (size_t)4 * N;       // [B,32]
    float* iou    = pooled + (size_t)B * 32;   // [B,1]

    float* ws      = (float*)d_ws;
    float* ws_sum  = ws;                 // 32
    float* ws_sq   = ws + 32;            // 32
    float* ws_pool = ws + 64;            // B*32
    float* ws_b1f  = ws + 64 + B * 32;   // 32
    float* ws_w1f  = ws + 96 + B * 32;   // 1024

    hipMemsetAsync(ws, 0, (size_t)(64 + B * 32) * sizeof(float), stream);

    pass1_kernel<<<1024, TPB, 0, stream>>>(feats, bidx, w1, b1, mw1, mb1, mw2, mb2,
                                           mask, ws_sum, ws_sq, ws_pool, N);
    finalize_kernel<<<1, TPB, 0, stream>>>(bidx, gamma, beta, w1, b1, iw, ib,
                                           ws_sum, ws_sq, ws_pool,
                                           ws_w1f, ws_b1f, pooled, iou, N, B);
    pass2_kernel<<<1024, TPB, 0, stream>>>(feats, ws_w1f, ws_b1f, w2, b2, pt, N);
}

// Round 2
// 474.753 us; speedup vs baseline: 1.2951x; 1.2951x over previous
//
#include <hip/hip_runtime.h>

#define TPB 256
#define NBLK 1024

typedef __attribute__((ext_vector_type(8))) short short8;
typedef __attribute__((ext_vector_type(4))) float floatx4;

__device__ __forceinline__ unsigned short bf_trunc(float f){
    union { float f; unsigned u; } c; c.f = f;
    return (unsigned short)(c.u >> 16);
}
__device__ __forceinline__ unsigned short bf_rne(float f){
    union { float f; unsigned u; } c; c.f = f;
    unsigned r = c.u + 0x7fffu + ((c.u >> 16) & 1u);
    return (unsigned short)(r >> 16);
}

// ---------------------------------------------------------------------------
// pass1: transposed MFMA  D = W^T * feats^T  (16x16x32 bf16).
//   A = weights (registers, loaded once), B = feats (2 coalesced float4/lane,
//   no LDS staging).  C cols = points, rows = out-channels:
//   - stats: out-channel fixed per lane -> pure register accumulation
//   - mask:  per-point sum -> 2 shfl_xor (across lane>>4 groups)
//   - pooled: f32 pre-conversion values, sorted-batch run accumulation
// ---------------------------------------------------------------------------
__global__ __launch_bounds__(TPB) void pass1_kernel(
    const float* __restrict__ feats, const int* __restrict__ bidx,
    const float* __restrict__ w1, const float* __restrict__ b1,
    const float* __restrict__ mw1, const float* __restrict__ mb1,
    const float* __restrict__ mw2, const float* __restrict__ mb2,
    float* __restrict__ mask_out,
    float* __restrict__ ws_sum, float* __restrict__ ws_sq,
    float* __restrict__ ws_pool, int N)
{
    __shared__ float s_pool[8][32];
    __shared__ float s_sum[32];
    __shared__ float s_sq[32];

    const int tid = threadIdx.x;
    if (tid < 32){ s_sum[tid] = 0.f; s_sq[tid] = 0.f; }
    ((float*)s_pool)[tid] = 0.f;           // TPB == 256 entries exactly
    __syncthreads();

    const int lane = tid & 63;
    const int p = lane & 15;               // point within tile (MFMA col)
    const int q = lane >> 4;               // k-group

    // A-fragments (weights) + C-inits (biases) + mw2 per-lane constants
    short8 aw0, aw1, am0, am1;
    floatx4 ci_h0, ci_h1, ci_m0, ci_m1;
    float mw2v[8];
#pragma unroll
    for (int j = 0; j < 8; ++j){
        const int k = q * 8 + j;
        aw0[j] = (short)bf_rne(w1 [k * 32 + p]);
        aw1[j] = (short)bf_rne(w1 [k * 32 + 16 + p]);
        am0[j] = (short)bf_rne(mw1[k * 32 + p]);
        am1[j] = (short)bf_rne(mw1[k * 32 + 16 + p]);
    }
#pragma unroll
    for (int r = 0; r < 4; ++r){
        const int c0 = q * 4 + r, c1 = 16 + q * 4 + r;
        ci_h0[r] = b1[c0];  ci_h1[r] = b1[c1];
        ci_m0[r] = mb1[c0]; ci_m1[r] = mb1[c1];
        mw2v[r] = mw2[c0];  mw2v[4 + r] = mw2[c1];
    }
    const float mb2s = mb2[0];

    float hsum[8] = {0,0,0,0,0,0,0,0};
    float hsq [8] = {0,0,0,0,0,0,0,0};
    float pacc[8] = {0,0,0,0,0,0,0,0};
    int curb = -1;

    const int  ntiles = (N + 15) >> 4;
    const long nw  = (long)gridDim.x * (TPB / 64);
    const long wid = (long)blockIdx.x * (TPB / 64) + (tid >> 6);
    const int  t0 = (int)(wid * (long)ntiles / nw);
    const int  t1 = (int)((wid + 1) * (long)ntiles / nw);

    for (int t = t0; t < t1; ++t){
        const int row0 = t << 4;
        const int row  = row0 + p;
        const bool valid = (row < N);

        floatx4 v0 = {0.f,0.f,0.f,0.f}, v1 = {0.f,0.f,0.f,0.f};
        if (valid){
            const floatx4* rp = (const floatx4*)(feats + (size_t)row * 32 + q * 8);
            v0 = rp[0]; v1 = rp[1];
        }

        // pooled on original f32 values (sorted batch -> rare flush)
        const int b = valid ? bidx[row] : -1;
        if (b != curb){
            if (curb >= 0){
#pragma unroll
                for (int j = 0; j < 8; ++j){
                    atomicAdd(&s_pool[curb][q * 8 + j], pacc[j]);
                    pacc[j] = 0.f;
                }
            }
            curb = b;
        }
        if (b >= 0){
            pacc[0] += v0[0]; pacc[1] += v0[1]; pacc[2] += v0[2]; pacc[3] += v0[3];
            pacc[4] += v1[0]; pacc[5] += v1[1]; pacc[6] += v1[2]; pacc[7] += v1[3];
        }

        // B-fragment (bf16 truncation; BN cancels the multiplicative bias)
        short8 bfrag;
        bfrag[0] = (short)bf_trunc(v0[0]); bfrag[1] = (short)bf_trunc(v0[1]);
        bfrag[2] = (short)bf_trunc(v0[2]); bfrag[3] = (short)bf_trunc(v0[3]);
        bfrag[4] = (short)bf_trunc(v1[0]); bfrag[5] = (short)bf_trunc(v1[1]);
        bfrag[6] = (short)bf_trunc(v1[2]); bfrag[7] = (short)bf_trunc(v1[3]);

        const floatx4 ch0 = __builtin_amdgcn_mfma_f32_16x16x32_bf16(aw0, bfrag, ci_h0, 0, 0, 0);
        const floatx4 ch1 = __builtin_amdgcn_mfma_f32_16x16x32_bf16(aw1, bfrag, ci_h1, 0, 0, 0);
        const floatx4 cm0 = __builtin_amdgcn_mfma_f32_16x16x32_bf16(am0, bfrag, ci_m0, 0, 0, 0);
        const floatx4 cm1 = __builtin_amdgcn_mfma_f32_16x16x32_bf16(am1, bfrag, ci_m1, 0, 0, 0);

        if (valid){
#pragma unroll
            for (int r = 0; r < 4; ++r){
                const float h0 = ch0[r]; hsum[r]     += h0; hsq[r]     = fmaf(h0, h0, hsq[r]);
                const float h1 = ch1[r]; hsum[4 + r] += h1; hsq[4 + r] = fmaf(h1, h1, hsq[4 + r]);
            }
        }

        // mask score: per-point partial over this lane's 8 out-channels
        float tm = 0.f;
#pragma unroll
        for (int r = 0; r < 4; ++r){
            tm = fmaf(fmaxf(cm0[r], 0.f), mw2v[r],     tm);
            tm = fmaf(fmaxf(cm1[r], 0.f), mw2v[4 + r], tm);
        }
        tm += __shfl_xor(tm, 16, 64);
        tm += __shfl_xor(tm, 32, 64);
        if (q == 0 && valid) mask_out[row] = tm + mb2s;
    }

    // final pooled flush
    if (curb >= 0){
#pragma unroll
        for (int j = 0; j < 8; ++j) atomicAdd(&s_pool[curb][q * 8 + j], pacc[j]);
    }
    // stats -> LDS -> global
#pragma unroll
    for (int i = 0; i < 8; ++i){
        const int ch = (i >> 2) * 16 + q * 4 + (i & 3);
        atomicAdd(&s_sum[ch], hsum[i]);
        atomicAdd(&s_sq[ch],  hsq[i]);
    }
    __syncthreads();
    if (tid < 32){
        atomicAdd(&ws_sum[tid], s_sum[tid]);
        atomicAdd(&ws_sq[tid],  s_sq[tid]);
    }
    {
        const float pv = ((float*)s_pool)[tid];
        if (pv != 0.f) atomicAdd(&ws_pool[tid], pv);
    }
}

// ---------------------------------------------------------------------------
// finalize: BN stats -> folded W1', b1' (f32, in ws); counts via binary search
// on sorted batch_idxs; pooled + iou outputs.  Single block.
// ---------------------------------------------------------------------------
__global__ __launch_bounds__(TPB) void finalize_kernel(
    const int* __restrict__ bidx,
    const float* __restrict__ gamma, const float* __restrict__ beta,
    const float* __restrict__ w1, const float* __restrict__ b1,
    const float* __restrict__ iw, const float* __restrict__ ib,
    const float* __restrict__ ws_sum, const float* __restrict__ ws_sq,
    const float* __restrict__ ws_pool,
    float* __restrict__ ws_w1f, float* __restrict__ ws_b1f,
    float* __restrict__ pooled_out, float* __restrict__ iou_out,
    int N, int B)
{
    __shared__ float s_s[32];
    __shared__ float s_pooled[256];
    __shared__ int   s_lb[33];

    const int tid = threadIdx.x;
    if (tid <= B){
        int lo = 0, hi = N;
        while (lo < hi){
            const int mid = (lo + hi) >> 1;
            if (bidx[mid] < tid) lo = mid + 1; else hi = mid;
        }
        s_lb[tid] = lo;
    }
    if (tid < 32){
        const float invN = 1.f / (float)N;
        const float mu  = ws_sum[tid] * invN;
        const float var = ws_sq[tid] * invN - mu * mu;
        const float s   = gamma[tid] * rsqrtf(var + 1e-4f);
        s_s[tid] = s;
        ws_b1f[tid] = (b1[tid] - mu) * s + beta[tid];
    }
    __syncthreads();
    for (int idx = tid; idx < 1024; idx += TPB)
        ws_w1f[idx] = w1[idx] * s_s[idx & 31];
    if (tid < B * 32){
        const int b = tid >> 5;
        const float cnt = fmaxf((float)(s_lb[b + 1] - s_lb[b]), 1.f);
        const float p = ws_pool[tid] / cnt;
        s_pooled[tid]   = p;
        pooled_out[tid] = p;
    }
    __syncthreads();
    if (tid < B){
        float acc = ib[0];
#pragma unroll
        for (int i = 0; i < 32; ++i) acc = fmaf(s_pooled[tid * 32 + i], iw[i], acc);
        iou_out[tid] = acc;
    }
}

// ---------------------------------------------------------------------------
// pass2: h' = feats@W1'+b1' (BN folded) via transposed MFMA, relu, @W2.
// pt projection: 24 register FMAs + 6 shfl_xor, store coalesced within 192B.
// ---------------------------------------------------------------------------
__global__ __launch_bounds__(TPB) void pass2_kernel(
    const float* __restrict__ feats,
    const float* __restrict__ ws_w1f, const float* __restrict__ ws_b1f,
    const float* __restrict__ w2, const float* __restrict__ b2,
    float* __restrict__ pt_out, int N)
{
    const int tid = threadIdx.x;
    const int lane = tid & 63;
    const int p = lane & 15;
    const int q = lane >> 4;

    short8 aw0, aw1;
    floatx4 ci0, ci1;
    float w2v[24];          // w2v[j*8 + i], i = w*4+r -> ch = w*16 + q*4 + r
    float b2v0, b2v1, b2v2;
#pragma unroll
    for (int j = 0; j < 8; ++j){
        const int k = q * 8 + j;
        aw0[j] = (short)bf_rne(ws_w1f[k * 32 + p]);
        aw1[j] = (short)bf_rne(ws_w1f[k * 32 + 16 + p]);
    }
#pragma unroll
    for (int r = 0; r < 4; ++r){
        ci0[r] = ws_b1f[q * 4 + r];
        ci1[r] = ws_b1f[16 + q * 4 + r];
    }
#pragma unroll
    for (int i = 0; i < 8; ++i){
        const int ch = (i >> 2) * 16 + q * 4 + (i & 3);
        w2v[i]      = w2[ch * 3 + 0];
        w2v[8 + i]  = w2[ch * 3 + 1];
        w2v[16 + i] = w2[ch * 3 + 2];
    }
    b2v0 = b2[0]; b2v1 = b2[1]; b2v2 = b2[2];

    const int  ntiles = (N + 15) >> 4;
    const long nw  = (long)gridDim.x * (TPB / 64);
    const long wid = (long)blockIdx.x * (TPB / 64) + (tid >> 6);
    const int  t0 = (int)(wid * (long)ntiles / nw);
    const int  t1 = (int)((wid + 1) * (long)ntiles / nw);

    for (int t = t0; t < t1; ++t){
        const int row0 = t << 4;
        const int row  = row0 + p;
        const bool valid = (row < N);

        floatx4 v0 = {0.f,0.f,0.f,0.f}, v1 = {0.f,0.f,0.f,0.f};
        if (valid){
            const floatx4* rp = (const floatx4*)(feats + (size_t)row * 32 + q * 8);
            v0 = rp[0]; v1 = rp[1];
        }
        short8 bfrag;
        bfrag[0] = (short)bf_trunc(v0[0]); bfrag[1] = (short)bf_trunc(v0[1]);
        bfrag[2] = (short)bf_trunc(v0[2]); bfrag[3] = (short)bf_trunc(v0[3]);
        bfrag[4] = (short)bf_trunc(v1[0]); bfrag[5] = (short)bf_trunc(v1[1]);
        bfrag[6] = (short)bf_trunc(v1[2]); bfrag[7] = (short)bf_trunc(v1[3]);

        const floatx4 c0 = __builtin_amdgcn_mfma_f32_16x16x32_bf16(aw0, bfrag, ci0, 0, 0, 0);
        const floatx4 c1 = __builtin_amdgcn_mfma_f32_16x16x32_bf16(aw1, bfrag, ci1, 0, 0, 0);

        float s0 = 0.f, s1 = 0.f, s2 = 0.f;
#pragma unroll
        for (int r = 0; r < 4; ++r){
            const float p0 = fmaxf(c0[r], 0.f);
            const float p1 = fmaxf(c1[r], 0.f);
            s0 = fmaf(p0, w2v[r],          s0); s0 = fmaf(p1, w2v[4 + r],      s0);
            s1 = fmaf(p0, w2v[8 + r],      s1); s1 = fmaf(p1, w2v[12 + r],     s1);
            s2 = fmaf(p0, w2v[16 + r],     s2); s2 = fmaf(p1, w2v[20 + r],     s2);
        }
        s0 += __shfl_xor(s0, 16, 64); s0 += __shfl_xor(s0, 32, 64);
        s1 += __shfl_xor(s1, 16, 64); s1 += __shfl_xor(s1, 32, 64);
        s2 += __shfl_xor(s2, 16, 64); s2 += __shfl_xor(s2, 32, 64);

        if (lane < 48 && valid){
            float val = (q == 0) ? (s0 + b2v0) : ((q == 1) ? (s1 + b2v1) : (s2 + b2v2));
            pt_out[(size_t)row0 * 3 + p * 3 + q] = val;
        }
    }
}

extern "C" void kernel_launch(void* const* d_in, const int* in_sizes, int n_in,
                              void* d_out, int out_size, void* d_ws, size_t ws_size,
                              hipStream_t stream) {
    const float* feats = (const float*)d_in[0];
    const int*   bidx  = (const int*)d_in[1];
    const float* w1    = (const float*)d_in[2];
    const float* b1    = (const float*)d_in[3];
    const float* gamma = (const float*)d_in[4];
    const float* beta  = (const float*)d_in[5];
    const float* w2    = (const float*)d_in[6];
    const float* b2    = (const float*)d_in[7];
    const float* mw1   = (const float*)d_in[8];
    const float* mb1   = (const float*)d_in[9];
    const float* mw2   = (const float*)d_in[10];
    const float* mb2   = (const float*)d_in[11];
    const float* iw    = (const float*)d_in[12];
    const float* ib    = (const float*)d_in[13];

    const int N = in_sizes[0] / 32;
    const int B = (out_size - 4 * N) / 33;   // out = 3N + N + 32B + B

    float* out    = (float*)d_out;
    float* pt     = out;                       // [N,3]
    float* mask   = out + (size_t)3 * N;       // [N,1]
    float* pooled = out + (size_t)4 * N;       // [B,32]
    float* iou    = pooled + (size_t)B * 32;   // [B,1]

    float* ws      = (float*)d_ws;
    float* ws_sum  = ws;                 // 32
    float* ws_sq   = ws + 32;            // 32
    float* ws_pool = ws + 64;            // B*32
    float* ws_b1f  = ws + 64 + B * 32;   // 32
    float* ws_w1f  = ws + 96 + B * 32;   // 1024

    hipMemsetAsync(ws, 0, (size_t)(64 + B * 32) * sizeof(float), stream);

    pass1_kernel<<<NBLK, TPB, 0, stream>>>(feats, bidx, w1, b1, mw1, mb1, mw2, mb2,
                                           mask, ws_sum, ws_sq, ws_pool, N);
    finalize_kernel<<<1, TPB, 0, stream>>>(bidx, gamma, beta, w1, b1, iw, ib,
                                           ws_sum, ws_sq, ws_pool,
                                           ws_w1f, ws_b1f, pooled, iou, N, B);
    pass2_kernel<<<NBLK, TPB, 0, stream>>>(feats, ws_w1f, ws_b1f, w2, b2, pt, N);
}